// Round 14
// baseline (454.334 us; speedup 1.0000x reference)
//
#include <hip/hip_runtime.h>
#include <hip/hip_bf16.h>
#include <math.h>

// ---------------------------------------------------------------------------
// GAT (3x GATConv, PyG-style) on MI355X. Round 14: r13 mega_kernel + race fix:
// layer-2 alpha logits get dedicated buffers (a2s/a2d) — in r13 they aliased
// the layer-1 alphas that other blocks were still gathering (cross-block WAR).
// mega = gather->LDS slab -> GEMM1 -> GEMM2 (+alpha2). 14 dispatches.
// ---------------------------------------------------------------------------

#define LEAKY_SLOPE 0.2f

typedef __attribute__((ext_vector_type(8))) short bf16x8;
typedef __attribute__((ext_vector_type(4))) float f32x4;
typedef __attribute__((ext_vector_type(4))) float fx4;

__device__ __forceinline__ unsigned short f2bf(float f) {
    unsigned int x = __float_as_uint(f);
    x += 0x7fffu + ((x >> 16) & 1u);   // RNE
    return (unsigned short)(x >> 16);
}
__device__ __forceinline__ float bf2f(unsigned short u) {
    return __uint_as_float(((unsigned int)u) << 16);
}
__device__ __forceinline__ float elu(float x) {  // cheap ELU: expf-1
    return (x > 0.f) ? x : (__expf(x) - 1.f);
}

__device__ __forceinline__ int edge_val(const int* __restrict__ ei, int is64, long long idx) {
    return is64 ? ei[2 * idx] : ei[idx];
}

__global__ void detect_kernel(const unsigned int* __restrict__ ei, int* __restrict__ flag) {
    int lane = threadIdx.x;
    unsigned int v = ei[2 * lane + 1];
    unsigned long long b = __ballot(v != 0u);
    if (lane == 0) *flag = (b == 0ull) ? 1 : 0;
}

__global__ __launch_bounds__(256) void zero2_kernel(int* __restrict__ a, int* __restrict__ b, int n) {
    int i = blockIdx.x * blockDim.x + threadIdx.x;
    if (i < n) { a[i] = 0; b[i] = 0; }
}

__global__ __launch_bounds__(256) void sentinel_kernel(float* __restrict__ out, int n, float v) {
    int i = blockIdx.x * blockDim.x + threadIdx.x;
    if (i < n) out[i] = v;
}

__global__ __launch_bounds__(256) void count_kernel(const int* __restrict__ ei,
                                                    const int* __restrict__ flag,
                                                    int E, int N, int* __restrict__ counts) {
    int e = blockIdx.x * blockDim.x + threadIdx.x;
    if (e >= E + N) return;
    int is64 = *flag;
    int d = (e < E) ? edge_val(ei, is64, (long long)E + e) : (e - E);
    atomicAdd(&counts[d], 1);
}

__global__ __launch_bounds__(256) void scan_block_kernel(const int* __restrict__ counts,
                                                         int* __restrict__ ptrArr,
                                                         int* __restrict__ bsums, int N) {
    __shared__ int sh[256];
    int t = threadIdx.x, i = blockIdx.x * 256 + t;
    int v = (i < N) ? counts[i] : 0;
    sh[t] = v;
    __syncthreads();
    for (int off = 1; off < 256; off <<= 1) {
        int u = (t >= off) ? sh[t - off] : 0;
        __syncthreads();
        sh[t] += u;
        __syncthreads();
    }
    if (i < N) ptrArr[i] = sh[t] - v;
    if (t == 255) bsums[blockIdx.x] = sh[255];
}

__global__ __launch_bounds__(1024) void scan_tops_kernel(const int* __restrict__ bsums,
                                                         int* __restrict__ boff, int nb,
                                                         int* __restrict__ totalOut) {
    __shared__ int sh[1024];
    int t = threadIdx.x;
    int v = (t < nb) ? bsums[t] : 0;
    sh[t] = v;
    __syncthreads();
    for (int off = 1; off < 1024; off <<= 1) {
        int u = (t >= off) ? sh[t - off] : 0;
        __syncthreads();
        sh[t] += u;
        __syncthreads();
    }
    if (t < nb) boff[t] = sh[t] - v;
    if (t == 1023) *totalOut = sh[1023];
}

__global__ __launch_bounds__(256) void scan_add_kernel(int* __restrict__ ptrArr,
                                                       const int* __restrict__ boff, int N) {
    int i = blockIdx.x * blockDim.x + threadIdx.x;
    if (i < N) ptrArr[i] += boff[i >> 8];
}

__global__ __launch_bounds__(256) void fill_kernel(const int* __restrict__ ei,
                                                   const int* __restrict__ flag,
                                                   int E, int N,
                                                   const int* __restrict__ ptrArr,
                                                   int* __restrict__ cursor,
                                                   int* __restrict__ csr_src) {
    int e = blockIdx.x * blockDim.x + threadIdx.x;
    if (e >= E + N) return;
    int is64 = *flag;
    int s, d;
    if (e < E) {
        s = edge_val(ei, is64, e);
        d = edge_val(ei, is64, (long long)E + e);
    } else {
        s = d = e - E;
    }
    int slot = atomicAdd(&cursor[d], 1);
    csr_src[ptrArr[d] + slot] = s;
}

// ---- W [K][N] fp32 -> Wt [N][K] bf16 ----
__global__ __launch_bounds__(256) void transpose_w_kernel(const float* __restrict__ W,
                                                          unsigned short* __restrict__ Wt,
                                                          int K, int Nn) {
    int i = blockIdx.x * blockDim.x + threadIdx.x;
    if (i >= K * Nn) return;
    int n = i / K, k = i - n * K;
    Wt[i] = f2bf(W[(size_t)k * Nn + n]);
}

// ---- ws1[k][h] = sum_c W1[k][h*128+c]*a_src1[h][c]; wd1 same with a_dst1 ----
__global__ __launch_bounds__(256) void proj_attn_kernel(const float* __restrict__ W1,
                                                        const float* __restrict__ a_s,
                                                        const float* __restrict__ a_d,
                                                        float* __restrict__ ws1,
                                                        float* __restrict__ wd1) {
    int t = blockIdx.x * blockDim.x + threadIdx.x;
    if (t >= 1024) return;
    int k = t >> 3, sd = (t >> 2) & 1, h = t & 3;
    const float* a = sd ? a_d : a_s;
    float s = 0.f;
    const float* wr = W1 + (size_t)k * 512 + h * 128;
    const float* ar = a + h * 128;
    for (int c = 0; c < 128; ++c) s += wr[c] * ar[c];
    (sd ? wd1 : ws1)[k * 4 + h] = s;
}

// ---- L1 alpha logits (fp32 exact) + x -> bf16 conversion fused ----
__global__ __launch_bounds__(256) void alpha_x_kernel(const float* __restrict__ x,
                                                      const float* __restrict__ ws1,
                                                      const float* __restrict__ wd1,
                                                      float* __restrict__ out_s,
                                                      float* __restrict__ out_d,
                                                      unsigned short* __restrict__ xbf, int N) {
    int lane = threadIdx.x & 63;
    int wid = threadIdx.x >> 6;
    int n = blockIdx.x * (blockDim.x >> 6) + wid;
    if (n >= N) return;
    int k0 = lane * 2;
    float2 xv = *(const float2*)(x + (size_t)n * 128 + k0);
    alignas(4) unsigned short o[2] = {f2bf(xv.x), f2bf(xv.y)};
    *(unsigned int*)(xbf + (size_t)n * 128 + k0) = *(unsigned int*)o;
    fx4 s0 = *(const fx4*)(ws1 + k0 * 4);
    fx4 s1 = *(const fx4*)(ws1 + k0 * 4 + 4);
    fx4 d0 = *(const fx4*)(wd1 + k0 * 4);
    fx4 d1 = *(const fx4*)(wd1 + k0 * 4 + 4);
    float ps[4], pd[4];
#pragma unroll
    for (int h = 0; h < 4; ++h) {
        ps[h] = xv.x * s0[h] + xv.y * s1[h];
        pd[h] = xv.x * d0[h] + xv.y * d1[h];
    }
#pragma unroll
    for (int off = 32; off; off >>= 1)
#pragma unroll
        for (int h = 0; h < 4; ++h) {
            ps[h] += __shfl_xor(ps[h], off);
            pd[h] += __shfl_xor(pd[h], off);
        }
    if (lane == 0) {
        fx4 rs = {ps[0], ps[1], ps[2], ps[3]};
        fx4 rd = {pd[0], pd[1], pd[2], pd[3]};
        *(fx4*)(out_s + (size_t)n * 4) = rs;
        *(fx4*)(out_d + (size_t)n * 4) = rd;
    }
}

// ---------------------------------------------------------------------------
// MEGA kernel: per 32-row block — (1) softmax+gather the 4 aggX head slabs
// into LDS, (2) phase A: h1 = ELU(slab @ W1 + b1) in LDS, (3) phase B:
// h2 = h1 @ W2 + alpha2 epilogue (written to DEDICATED a2s/a2d buffers).
// 8 waves, 74 KB LDS (2 blocks/CU). Transposed-output MFMA.
// ---------------------------------------------------------------------------
__global__ __launch_bounds__(512, 4) void mega_kernel(const int* __restrict__ ptrArr,
                                                      const int* __restrict__ csr_src,
                                                      const float* __restrict__ as1,
                                                      const float* __restrict__ ad1,
                                                      const unsigned short* __restrict__ xbf,
                                                      const unsigned short* __restrict__ Wt1,
                                                      const unsigned short* __restrict__ Wt2,
                                                      const float* __restrict__ b1,
                                                      const float* __restrict__ a_src2,
                                                      const float* __restrict__ a_dst2,
                                                      unsigned short* __restrict__ h2,
                                                      float* __restrict__ a2s,
                                                      float* __restrict__ a2d,
                                                      int M) {
    __shared__ unsigned short slab[4 * 32 * 128];  // 32 KB: [head][row32][128]
    __shared__ unsigned short h1[32 * 512];        // 32 KB, row stride 1024 B
    __shared__ float sal[8][64][4];                // 8 KB gather alpha buffer
    __shared__ float red[8 * 2 * 32];              // 2 KB alpha2 scratch
    const int bm = blockIdx.x;
    const int tid = threadIdx.x;
    const int lane = tid & 63, wid = tid >> 6;     // wid in [0,8)
    const int h = wid >> 1, half = wid & 1;
    const int l15 = lane & 15, l4 = lane >> 4;

    // ================= gather phase: wave wid owns rows wid*4..+3 ==========
    for (int i = 0; i < 4; ++i) {
        int r = wid * 4 + i;
        int n = bm * 32 + r;
        float acc[4][2];
#pragma unroll
        for (int hh = 0; hh < 4; ++hh) { acc[hh][0] = 0.f; acc[hh][1] = 0.f; }
        if (n < M) {
            int beg = ptrArr[n], end = ptrArr[n + 1];
            int deg = end - beg;
            fx4 dv = *(const fx4*)(ad1 + (size_t)n * 4);
            if (deg <= 64) {
                bool act = lane < deg;
                int ii = beg + (act ? lane : 0);
                int s = csr_src[ii];
                fx4 av = *(const fx4*)(as1 + (size_t)s * 4);
                float e[4];
#pragma unroll
                for (int hh = 0; hh < 4; ++hh) {
                    float xx = av[hh] + dv[hh];
                    xx = (xx >= 0.f) ? xx : LEAKY_SLOPE * xx;
                    e[hh] = act ? xx : -INFINITY;
                }
#pragma unroll
                for (int hh = 0; hh < 4; ++hh) {
                    float mm = e[hh];
#pragma unroll
                    for (int off = 32; off; off >>= 1) mm = fmaxf(mm, __shfl_xor(mm, off));
                    float ex = __expf(e[hh] - mm);
                    float ss = ex;
#pragma unroll
                    for (int off = 32; off; off >>= 1) ss += __shfl_xor(ss, off);
                    sal[wid][lane][hh] = ex / (ss + 1e-16f);
                }
                for (int i2 = beg; i2 < end; i2 += 4) {
                    int rr = end - i2;
                    int e1 = (rr > 1) ? i2 + 1 : i2;
                    int e2 = (rr > 2) ? i2 + 2 : i2;
                    int e3 = (rr > 3) ? i2 + 3 : i2;
                    int s0 = csr_src[i2], s1 = csr_src[e1], s2 = csr_src[e2], s3 = csr_src[e3];
                    fx4 a0 = *(const fx4*)&sal[wid][i2 - beg][0];
                    fx4 a1 = *(const fx4*)&sal[wid][e1 - beg][0];
                    fx4 a2 = *(const fx4*)&sal[wid][e2 - beg][0];
                    fx4 a3 = *(const fx4*)&sal[wid][e3 - beg][0];
                    if (rr <= 1) a1 = (fx4){0.f, 0.f, 0.f, 0.f};
                    if (rr <= 2) a2 = (fx4){0.f, 0.f, 0.f, 0.f};
                    if (rr <= 3) a3 = (fx4){0.f, 0.f, 0.f, 0.f};
                    unsigned int r0 = *(const unsigned int*)(xbf + (size_t)s0 * 128 + lane * 2);
                    unsigned int r1 = *(const unsigned int*)(xbf + (size_t)s1 * 128 + lane * 2);
                    unsigned int r2 = *(const unsigned int*)(xbf + (size_t)s2 * 128 + lane * 2);
                    unsigned int r3 = *(const unsigned int*)(xbf + (size_t)s3 * 128 + lane * 2);
                    float x00 = bf2f((unsigned short)r0), x01 = bf2f((unsigned short)(r0 >> 16));
                    float x10 = bf2f((unsigned short)r1), x11 = bf2f((unsigned short)(r1 >> 16));
                    float x20 = bf2f((unsigned short)r2), x21 = bf2f((unsigned short)(r2 >> 16));
                    float x30 = bf2f((unsigned short)r3), x31 = bf2f((unsigned short)(r3 >> 16));
#pragma unroll
                    for (int hh = 0; hh < 4; ++hh) {
                        acc[hh][0] += a0[hh] * x00 + a1[hh] * x10 + a2[hh] * x20 + a3[hh] * x30;
                        acc[hh][1] += a0[hh] * x01 + a1[hh] * x11 + a2[hh] * x21 + a3[hh] * x31;
                    }
                }
            } else {
                float m[4], inv[4];
#pragma unroll
                for (int hh = 0; hh < 4; ++hh) m[hh] = -INFINITY;
                for (int ii = beg + lane; ii < end; ii += 64) {
                    int s = csr_src[ii];
                    fx4 av = *(const fx4*)(as1 + (size_t)s * 4);
#pragma unroll
                    for (int hh = 0; hh < 4; ++hh) {
                        float v = av[hh] + dv[hh];
                        v = (v >= 0.f) ? v : LEAKY_SLOPE * v;
                        m[hh] = fmaxf(m[hh], v);
                    }
                }
#pragma unroll
                for (int hh = 0; hh < 4; ++hh)
#pragma unroll
                    for (int off = 32; off; off >>= 1) m[hh] = fmaxf(m[hh], __shfl_xor(m[hh], off));
                float ss[4] = {0.f, 0.f, 0.f, 0.f};
                for (int ii = beg + lane; ii < end; ii += 64) {
                    int s = csr_src[ii];
                    fx4 av = *(const fx4*)(as1 + (size_t)s * 4);
#pragma unroll
                    for (int hh = 0; hh < 4; ++hh) {
                        float v = av[hh] + dv[hh];
                        v = (v >= 0.f) ? v : LEAKY_SLOPE * v;
                        ss[hh] += __expf(v - m[hh]);
                    }
                }
#pragma unroll
                for (int hh = 0; hh < 4; ++hh) {
#pragma unroll
                    for (int off = 32; off; off >>= 1) ss[hh] += __shfl_xor(ss[hh], off);
                    inv[hh] = 1.f / (ss[hh] + 1e-16f);
                }
                for (int ii = beg; ii < end; ++ii) {
                    int s = csr_src[ii];
                    fx4 av = *(const fx4*)(as1 + (size_t)s * 4);
                    unsigned int rr = *(const unsigned int*)(xbf + (size_t)s * 128 + lane * 2);
                    float x0 = bf2f((unsigned short)rr), x1 = bf2f((unsigned short)(rr >> 16));
#pragma unroll
                    for (int hh = 0; hh < 4; ++hh) {
                        float v = av[hh] + dv[hh];
                        v = (v >= 0.f) ? v : LEAKY_SLOPE * v;
                        float al = __expf(v - m[hh]) * inv[hh];
                        acc[hh][0] += al * x0;
                        acc[hh][1] += al * x1;
                    }
                }
            }
        }
        // write slab: dword at [head][r][lane*2..+1], byte col XOR (r&7)<<4
        int byteoff = (lane * 4) ^ ((r & 7) << 4);
#pragma unroll
        for (int hh = 0; hh < 4; ++hh) {
            alignas(4) unsigned short o[2] = {f2bf(acc[hh][0]), f2bf(acc[hh][1])};
            *(unsigned int*)((char*)slab + hh * 8192 + r * 256 + byteoff) = *(unsigned int*)o;
        }
    }
    __syncthreads();  // slab complete

    // ================= phase A: h1 cols [h*128+half*64, +64), K=128 ========
    {
        const char* Asw = (const char*)slab + h * 8192;
        f32x4 acc[2][4];
#pragma unroll
        for (int m = 0; m < 2; ++m)
#pragma unroll
            for (int n = 0; n < 4; ++n) acc[m][n] = (f32x4){0.f, 0.f, 0.f, 0.f};
#pragma unroll
        for (int step = 0; step < 4; ++step) {
            bf16x8 af[2], bfr[4];
            int kb = step * 64 + l4 * 16;
#pragma unroll
            for (int m = 0; m < 2; ++m) {
                int rl = m * 16 + l15;
                af[m] = *(const bf16x8*)(Asw + rl * 256 + (kb ^ ((rl & 7) << 4)));
            }
#pragma unroll
            for (int n = 0; n < 4; ++n) {
                int rB = h * 128 + half * 64 + n * 16 + l15;
                bfr[n] = *(const bf16x8*)(Wt1 + (size_t)rB * 128 + step * 32 + l4 * 8);
            }
#pragma unroll
            for (int m = 0; m < 2; ++m)
#pragma unroll
                for (int n = 0; n < 4; ++n)
                    acc[m][n] = __builtin_amdgcn_mfma_f32_16x16x32_bf16(bfr[n], af[m], acc[m][n], 0, 0, 0);
        }
        // ELU(+bias) -> h1 LDS (XOR-swizzled rows, stride 1024B)
#pragma unroll
        for (int m = 0; m < 2; ++m) {
            int rl = m * 16 + l15;
#pragma unroll
            for (int n = 0; n < 4; ++n) {
                int col = h * 128 + half * 64 + n * 16 + l4 * 4;
                fx4 bb = *(const fx4*)(b1 + col);
                f32x4 v = acc[m][n];
                alignas(8) unsigned short o[4];
#pragma unroll
                for (int j = 0; j < 4; ++j) o[j] = f2bf(elu(v[j] + bb[j]));
                int byteoff = (col * 2) ^ ((rl & 7) << 4);
                *(uint2*)((char*)h1 + rl * 1024 + byteoff) = *(uint2*)o;
            }
        }
    }
    __syncthreads();  // h1 complete

    // ================= phase B: h2 cols [h*64+half*32, +32), K=512 =========
    f32x4 acc2[2][2];
#pragma unroll
    for (int m = 0; m < 2; ++m)
#pragma unroll
        for (int n = 0; n < 2; ++n) acc2[m][n] = (f32x4){0.f, 0.f, 0.f, 0.f};
#pragma unroll 4
    for (int step = 0; step < 16; ++step) {
        bf16x8 af[2], bfr[2];
        int kb = step * 64 + l4 * 16;
#pragma unroll
        for (int m = 0; m < 2; ++m) {
            int rl = m * 16 + l15;
            af[m] = *(const bf16x8*)((const char*)h1 + rl * 1024 + (kb ^ ((rl & 7) << 4)));
        }
#pragma unroll
        for (int n = 0; n < 2; ++n) {
            int rB = h * 64 + half * 32 + n * 16 + l15;
            bfr[n] = *(const bf16x8*)(Wt2 + (size_t)rB * 512 + step * 32 + l4 * 8);
        }
#pragma unroll
        for (int m = 0; m < 2; ++m)
#pragma unroll
            for (int n = 0; n < 2; ++n)
                acc2[m][n] = __builtin_amdgcn_mfma_f32_16x16x32_bf16(bfr[n], af[m], acc2[m][n], 0, 0, 0);
    }
    // ---- store h2 (packed 8B) ----
#pragma unroll
    for (int m = 0; m < 2; ++m) {
        int row = bm * 32 + m * 16 + l15;
        if (row < M) {
#pragma unroll
            for (int n = 0; n < 2; ++n) {
                int col = h * 64 + half * 32 + n * 16 + l4 * 4;
                f32x4 v = acc2[m][n];
                alignas(8) unsigned short o[4] = {f2bf(v[0]), f2bf(v[1]), f2bf(v[2]), f2bf(v[3])};
                *(uint2*)(h2 + (size_t)row * 256 + col) = *(uint2*)o;
            }
        }
    }
    // ---- alpha2 partials (wave covers 32 of head h's 64 cols) ----
    float ps[2], pd[2];
#pragma unroll
    for (int m = 0; m < 2; ++m) { ps[m] = 0.f; pd[m] = 0.f; }
#pragma unroll
    for (int n = 0; n < 2; ++n) {
        int col = h * 64 + half * 32 + n * 16 + l4 * 4;
        fx4 asv = *(const fx4*)(a_src2 + col);
        fx4 adv = *(const fx4*)(a_dst2 + col);
#pragma unroll
        for (int m = 0; m < 2; ++m)
#pragma unroll
            for (int j = 0; j < 4; ++j) {
                ps[m] += acc2[m][n][j] * asv[j];
                pd[m] += acc2[m][n][j] * adv[j];
            }
    }
#pragma unroll
    for (int m = 0; m < 2; ++m) {
        ps[m] += __shfl_xor(ps[m], 16); ps[m] += __shfl_xor(ps[m], 32);
        pd[m] += __shfl_xor(pd[m], 16); pd[m] += __shfl_xor(pd[m], 32);
    }
    if (lane < 16) {
#pragma unroll
        for (int m = 0; m < 2; ++m) {
            int rl = m * 16 + l15;
            red[(wid * 2 + 0) * 32 + rl] = ps[m];
            red[(wid * 2 + 1) * 32 + rl] = pd[m];
        }
    }
    __syncthreads();
    if (half == 0 && lane < 16) {
#pragma unroll
        for (int m = 0; m < 2; ++m) {
            int rl = m * 16 + l15;
            int row = bm * 32 + rl;
            if (row < M) {
                a2s[(size_t)row * 4 + h] = red[(wid * 2 + 0) * 32 + rl] + red[((wid + 1) * 2 + 0) * 32 + rl];
                a2d[(size_t)row * 4 + h] = red[(wid * 2 + 1) * 32 + rl] + red[((wid + 1) * 2 + 1) * 32 + rl];
            }
        }
    }
}

// ---------------------------------------------------------------------------
// Fused softmax + aggregate (layer 2) + layer-3 GEMM + alpha3 epilogue.
// ---------------------------------------------------------------------------
__global__ __launch_bounds__(256) void sm_agg2_kernel(const int* __restrict__ ptrArr,
                                                      const int* __restrict__ csr_src,
                                                      const float* __restrict__ as,
                                                      const float* __restrict__ ad,
                                                      const unsigned short* __restrict__ hmat,
                                                      const float* __restrict__ bias,
                                                      const float* __restrict__ W3,
                                                      const float* __restrict__ a_s3,
                                                      const float* __restrict__ a_d3,
                                                      float* __restrict__ h3,
                                                      float* __restrict__ alpha_s3,
                                                      float* __restrict__ alpha_d3, int N) {
    __shared__ float sal[4][64][4];
    int lane = threadIdx.x & 63;
    int wid = threadIdx.x >> 6;
    int n = blockIdx.x * 4 + wid;
    if (n >= N) return;
    int beg = ptrArr[n], end = ptrArr[n + 1];
    int deg = end - beg;
    int head = lane >> 4;
    fx4 dv = *(const fx4*)(ad + (size_t)n * 4);
    float acc[4] = {0.f, 0.f, 0.f, 0.f};

    if (deg <= 64) {
        bool act = lane < deg;
        int i = beg + (act ? lane : 0);
        int s = csr_src[i];
        fx4 av = *(const fx4*)(as + (size_t)s * 4);
        float e[4];
#pragma unroll
        for (int h = 0; h < 4; ++h) {
            float xx = av[h] + dv[h];
            xx = (xx >= 0.f) ? xx : LEAKY_SLOPE * xx;
            e[h] = act ? xx : -INFINITY;
        }
#pragma unroll
        for (int h = 0; h < 4; ++h) {
            float mm = e[h];
#pragma unroll
            for (int off = 32; off; off >>= 1) mm = fmaxf(mm, __shfl_xor(mm, off));
            float ex = __expf(e[h] - mm);
            float ss = ex;
#pragma unroll
            for (int off = 32; off; off >>= 1) ss += __shfl_xor(ss, off);
            sal[wid][lane][h] = ex / (ss + 1e-16f);
        }
        for (int i2 = beg; i2 < end; i2 += 4) {
            int r = end - i2;
            int e1 = (r > 1) ? i2 + 1 : i2;
            int e2 = (r > 2) ? i2 + 2 : i2;
            int e3 = (r > 3) ? i2 + 3 : i2;
            int s0 = csr_src[i2], s1 = csr_src[e1], s2 = csr_src[e2], s3 = csr_src[e3];
            float al0 = sal[wid][i2 - beg][head];
            float al1 = (r > 1) ? sal[wid][e1 - beg][head] : 0.f;
            float al2 = (r > 2) ? sal[wid][e2 - beg][head] : 0.f;
            float al3 = (r > 3) ? sal[wid][e3 - beg][head] : 0.f;
            alignas(8) unsigned short v0[4], v1[4], v2[4], v3[4];
            *(uint2*)v0 = *(const uint2*)(hmat + (size_t)s0 * 256 + lane * 4);
            *(uint2*)v1 = *(const uint2*)(hmat + (size_t)s1 * 256 + lane * 4);
            *(uint2*)v2 = *(const uint2*)(hmat + (size_t)s2 * 256 + lane * 4);
            *(uint2*)v3 = *(const uint2*)(hmat + (size_t)s3 * 256 + lane * 4);
#pragma unroll
            for (int t = 0; t < 4; ++t)
                acc[t] += al0 * bf2f(v0[t]) + al1 * bf2f(v1[t]) + al2 * bf2f(v2[t]) + al3 * bf2f(v3[t]);
        }
    } else {
        float m[4], inv[4];
#pragma unroll
        for (int h = 0; h < 4; ++h) m[h] = -INFINITY;
        for (int i = beg + lane; i < end; i += 64) {
            int s = csr_src[i];
            fx4 av = *(const fx4*)(as + (size_t)s * 4);
#pragma unroll
            for (int h = 0; h < 4; ++h) {
                float v = av[h] + dv[h];
                v = (v >= 0.f) ? v : LEAKY_SLOPE * v;
                m[h] = fmaxf(m[h], v);
            }
        }
#pragma unroll
        for (int h = 0; h < 4; ++h)
#pragma unroll
            for (int off = 32; off; off >>= 1) m[h] = fmaxf(m[h], __shfl_xor(m[h], off));
        float ss[4] = {0.f, 0.f, 0.f, 0.f};
        for (int i = beg + lane; i < end; i += 64) {
            int s = csr_src[i];
            fx4 av = *(const fx4*)(as + (size_t)s * 4);
#pragma unroll
            for (int h = 0; h < 4; ++h) {
                float v = av[h] + dv[h];
                v = (v >= 0.f) ? v : LEAKY_SLOPE * v;
                ss[h] += __expf(v - m[h]);
            }
        }
#pragma unroll
        for (int h = 0; h < 4; ++h) {
#pragma unroll
            for (int off = 32; off; off >>= 1) ss[h] += __shfl_xor(ss[h], off);
            inv[h] = 1.f / (ss[h] + 1e-16f);
        }
        float mh = m[head], invh = inv[head];
        float adh = dv[head];
        for (int i = beg; i < end; ++i) {
            int s = csr_src[i];
            float v = as[(size_t)s * 4 + head] + adh;
            v = (v >= 0.f) ? v : LEAKY_SLOPE * v;
            float al = __expf(v - mh) * invh;
            alignas(8) unsigned short vv[4];
            *(uint2*)vv = *(const uint2*)(hmat + (size_t)s * 256 + lane * 4);
#pragma unroll
            for (int t = 0; t < 4; ++t) acc[t] += al * bf2f(vv[t]);
        }
    }
    // ---- x3 row in registers: ELU(+bias); then layer-3 dot (2 cols) ----
    float xv[4];
#pragma unroll
    for (int t = 0; t < 4; ++t) xv[t] = elu(acc[t] + bias[lane * 4 + t]);
    int j0 = lane * 4;
    fx4 wA = *(const fx4*)(W3 + j0 * 2);
    fx4 wB = *(const fx4*)(W3 + j0 * 2 + 4);
    float p0 = xv[0] * wA[0] + xv[1] * wA[2] + xv[2] * wB[0] + xv[3] * wB[2];
    float p1 = xv[0] * wA[1] + xv[1] * wA[3] + xv[2] * wB[1] + xv[3] * wB[3];
#pragma unroll
    for (int off = 32; off; off >>= 1) {
        p0 += __shfl_xor(p0, off);
        p1 += __shfl_xor(p1, off);
    }
    if (lane == 0) {
        h3[(size_t)n * 2 + 0] = p0;
        h3[(size_t)n * 2 + 1] = p1;
        alpha_s3[n] = p0 * a_s3[0] + p1 * a_s3[1];
        alpha_d3[n] = p0 * a_d3[0] + p1 * a_d3[1];
    }
}

// ---------------------------------------------------------------------------
// Fused softmax + aggregate (layer 3, H=1, out fp32). Wave per node.
// ---------------------------------------------------------------------------
__global__ __launch_bounds__(256) void sm_agg3_kernel(const int* __restrict__ ptrArr,
                                                      const int* __restrict__ csr_src,
                                                      const float* __restrict__ as,
                                                      const float* __restrict__ ad,
                                                      const float* __restrict__ h3,
                                                      const float* __restrict__ b3,
                                                      float* __restrict__ out, int N) {
    int lane = threadIdx.x & 63;
    int wid = threadIdx.x >> 6;
    int n = blockIdx.x * 4 + wid;
    if (n >= N) return;
    int beg = ptrArr[n], end = ptrArr[n + 1];
    int deg = end - beg;
    float adv = ad[n];
    float p0 = 0.f, p1 = 0.f;
    if (deg <= 64) {
        bool act = lane < deg;
        int i = beg + (act ? lane : 0);
        int s = csr_src[i];
        float xx = as[s] + adv;
        xx = (xx >= 0.f) ? xx : LEAKY_SLOPE * xx;
        float e = act ? xx : -INFINITY;
        float mm = e;
#pragma unroll
        for (int off = 32; off; off >>= 1) mm = fmaxf(mm, __shfl_xor(mm, off));
        float ex = __expf(e - mm);
        float ss = ex;
#pragma unroll
        for (int off = 32; off; off >>= 1) ss += __shfl_xor(ss, off);
        float al = ex / (ss + 1e-16f);
        float2 hv = act ? *(const float2*)(h3 + (size_t)s * 2) : make_float2(0.f, 0.f);
        p0 = al * hv.x;
        p1 = al * hv.y;
#pragma unroll
        for (int off = 32; off; off >>= 1) {
            p0 += __shfl_xor(p0, off);
            p1 += __shfl_xor(p1, off);
        }
    } else {
        float m = -INFINITY;
        for (int i = beg + lane; i < end; i += 64) {
            int s = csr_src[i];
            float v = as[s] + adv;
            v = (v >= 0.f) ? v : LEAKY_SLOPE * v;
            m = fmaxf(m, v);
        }
#pragma unroll
        for (int off = 32; off; off >>= 1) m = fmaxf(m, __shfl_xor(m, off));
        float ss = 0.f;
        for (int i = beg + lane; i < end; i += 64) {
            int s = csr_src[i];
            float v = as[s] + adv;
            v = (v >= 0.f) ? v : LEAKY_SLOPE * v;
            ss += __expf(v - m);
        }
#pragma unroll
        for (int off = 32; off; off >>= 1) ss += __shfl_xor(ss, off);
        float inv = 1.f / (ss + 1e-16f);
        for (int i = beg + lane; i < end; i += 64) {
            int s = csr_src[i];
            float v = as[s] + adv;
            v = (v >= 0.f) ? v : LEAKY_SLOPE * v;
            float al = __expf(v - m) * inv;
            float2 hv = *(const float2*)(h3 + (size_t)s * 2);
            p0 += al * hv.x;
            p1 += al * hv.y;
        }
#pragma unroll
        for (int off = 32; off; off >>= 1) {
            p0 += __shfl_xor(p0, off);
            p1 += __shfl_xor(p1, off);
        }
    }
    if (lane == 0) {
        out[(size_t)n * 2 + 0] = p0 + b3[0];
        out[(size_t)n * 2 + 1] = p1 + b3[1];
    }
}

// ---------------------------------------------------------------------------

extern "C" void kernel_launch(void* const* d_in, const int* in_sizes, int n_in,
                              void* d_out, int out_size, void* d_ws, size_t ws_size,
                              hipStream_t stream) {
    const float* x      = (const float*)d_in[0];
    const int*   ei     = (const int*)d_in[1];
    const float* W1     = (const float*)d_in[2];
    const float* a_src1 = (const float*)d_in[3];
    const float* a_dst1 = (const float*)d_in[4];
    const float* b1     = (const float*)d_in[5];
    const float* W2     = (const float*)d_in[6];
    const float* a_src2 = (const float*)d_in[7];
    const float* a_dst2 = (const float*)d_in[8];
    const float* b2     = (const float*)d_in[9];
    const float* W3     = (const float*)d_in[10];
    const float* a_src3 = (const float*)d_in[11];
    const float* a_dst3 = (const float*)d_in[12];
    const float* b3     = (const float*)d_in[13];

    const int N = in_sizes[0] / 128;
    const int E = in_sizes[1] / 2;
    const int ET = E + N;
    const int nb = (N + 255) / 256;

    size_t need = 0;
    auto carve = [&](size_t bytes) -> size_t {
        size_t off = need;
        need += (bytes + 255) & ~(size_t)255;
        return off;
    };
    size_t o_counts   = carve((size_t)N * 4);
    size_t o_cursor   = carve((size_t)N * 4);
    size_t o_ptr      = carve((size_t)(N + 1) * 4);
    size_t o_csr      = carve((size_t)ET * 4);
    size_t o_flag     = carve(4);
    size_t o_bsums    = carve((size_t)2048 * 4);
    size_t o_boff     = carve((size_t)2048 * 4);
    size_t o_alpha_s  = carve((size_t)N * 4 * 4);
    size_t o_alpha_d  = carve((size_t)N * 4 * 4);
    size_t o_a2s      = carve((size_t)N * 4 * 4);
    size_t o_a2d      = carve((size_t)N * 4 * 4);
    size_t o_a3s      = carve((size_t)N * 4);
    size_t o_a3d      = carve((size_t)N * 4);
    size_t o_h3       = carve((size_t)N * 2 * 4);
    size_t o_wsd      = carve((size_t)128 * 4 * 4 * 2);  // ws1 + wd1
    size_t o_wt1      = carve((size_t)512 * 128 * 2);
    size_t o_wt2      = carve((size_t)256 * 512 * 2);
    size_t o_xbf      = carve((size_t)N * 128 * 2);
    size_t o_bufB     = carve((size_t)N * 512 * 2);

    if (need > ws_size) {
        sentinel_kernel<<<(out_size + 255) / 256, 256, 0, stream>>>(
            (float*)d_out, out_size, (float)(ws_size >> 20));
        return;
    }

    char* w = (char*)d_ws;
    int*   counts   = (int*)(w + o_counts);
    int*   cursor   = (int*)(w + o_cursor);
    int*   ptrArr   = (int*)(w + o_ptr);
    int*   csr_src  = (int*)(w + o_csr);
    int*   flag     = (int*)(w + o_flag);
    int*   bsums    = (int*)(w + o_bsums);
    int*   boff     = (int*)(w + o_boff);
    float* alpha_s  = (float*)(w + o_alpha_s);
    float* alpha_d  = (float*)(w + o_alpha_d);
    float* a2s      = (float*)(w + o_a2s);
    float* a2d      = (float*)(w + o_a2d);
    float* a3s      = (float*)(w + o_a3s);
    float* a3d      = (float*)(w + o_a3d);
    float* h3       = (float*)(w + o_h3);
    float* ws1      = (float*)(w + o_wsd);
    float* wd1      = ws1 + 128 * 4;
    unsigned short* Wt1  = (unsigned short*)(w + o_wt1);
    unsigned short* Wt2  = (unsigned short*)(w + o_wt2);
    unsigned short* xbf  = (unsigned short*)(w + o_xbf);
    unsigned short* bufB = (unsigned short*)(w + o_bufB);

    const int edge_blocks = (ET + 255) / 256;
    const int node_wave_blocks = (N + 3) / 4;
    const int node_thr_blocks = (N + 255) / 256;

    // ---- CSR build ----
    zero2_kernel<<<node_thr_blocks, 256, 0, stream>>>(counts, cursor, N);
    detect_kernel<<<1, 64, 0, stream>>>((const unsigned int*)ei, flag);
    count_kernel<<<edge_blocks, 256, 0, stream>>>(ei, flag, E, N, counts);
    scan_block_kernel<<<nb, 256, 0, stream>>>(counts, ptrArr, bsums, N);
    scan_tops_kernel<<<1, 1024, 0, stream>>>(bsums, boff, nb, ptrArr + N);
    scan_add_kernel<<<node_thr_blocks, 256, 0, stream>>>(ptrArr, boff, N);
    fill_kernel<<<edge_blocks, 256, 0, stream>>>(ei, flag, E, N, ptrArr, cursor, csr_src);

    // ---- precomputes ----
    transpose_w_kernel<<<(512 * 128 + 255) / 256, 256, 0, stream>>>(W1, Wt1, 128, 512);
    transpose_w_kernel<<<(256 * 512 + 255) / 256, 256, 0, stream>>>(W2, Wt2, 512, 256);
    proj_attn_kernel<<<4, 256, 0, stream>>>(W1, a_src1, a_dst1, ws1, wd1);

    // ---- alpha1 logits + x->bf16 ----
    alpha_x_kernel<<<node_wave_blocks, 256, 0, stream>>>(x, ws1, wd1, alpha_s, alpha_d, xbf, N);

    // ---- MEGA: gather+GEMM1+GEMM2 -> h2(bufB) + alpha2 (separate bufs) ----
    mega_kernel<<<(N + 31) / 32, 512, 0, stream>>>(ptrArr, csr_src, alpha_s, alpha_d, xbf,
                                                   Wt1, Wt2, b1, a_src2, a_dst2,
                                                   bufB, a2s, a2d, N);

    // ---- Layer 2 back half + layer-3 GEMM + alpha3 ----
    sm_agg2_kernel<<<node_wave_blocks, 256, 0, stream>>>(ptrArr, csr_src, a2s, a2d,
                                                         bufB, b2, W3, a_src3, a_dst3,
                                                         h3, a3s, a3d, N);

    // ---- Layer 3 aggregate ----
    sm_agg3_kernel<<<node_wave_blocks, 256, 0, stream>>>(ptrArr, csr_src, a3s, a3d, h3, b3, (float*)d_out, N);
}

// Round 15
// 408.364 us; speedup vs baseline: 1.1126x; 1.1126x over previous
//
#include <hip/hip_runtime.h>
#include <hip/hip_bf16.h>
#include <math.h>

// ---------------------------------------------------------------------------
// GAT (3x GATConv, PyG-style) on MI355X. Round 15: revert to r12 structure
// (mega_kernel regressed: in-block gather serialization > traffic win).
// r12 + dedicated a2s/a2d buffers + merged precompute dispatches
// (prep_graph = zero+detect, prep_weights = Wt1+Wt2+proj). 12 dispatches.
// ---------------------------------------------------------------------------

#define LEAKY_SLOPE 0.2f

typedef __attribute__((ext_vector_type(8))) short bf16x8;
typedef __attribute__((ext_vector_type(4))) float f32x4;
typedef __attribute__((ext_vector_type(4))) float fx4;

__device__ __forceinline__ unsigned short f2bf(float f) {
    unsigned int x = __float_as_uint(f);
    x += 0x7fffu + ((x >> 16) & 1u);   // RNE
    return (unsigned short)(x >> 16);
}
__device__ __forceinline__ float bf2f(unsigned short u) {
    return __uint_as_float(((unsigned int)u) << 16);
}
__device__ __forceinline__ float elu(float x) {  // cheap ELU: expf-1
    return (x > 0.f) ? x : (__expf(x) - 1.f);
}

__device__ __forceinline__ int edge_val(const int* __restrict__ ei, int is64, long long idx) {
    return is64 ? ei[2 * idx] : ei[idx];
}

__global__ __launch_bounds__(256) void sentinel_kernel(float* __restrict__ out, int n, float v) {
    int i = blockIdx.x * blockDim.x + threadIdx.x;
    if (i < n) out[i] = v;
}

// ---- merged: zero counts/cursor + int64 detect (block 0, wave 0) ----
__global__ __launch_bounds__(256) void prep_graph_kernel(const unsigned int* __restrict__ ei,
                                                         int* __restrict__ flag,
                                                         int* __restrict__ counts,
                                                         int* __restrict__ cursor, int n) {
    int i = blockIdx.x * blockDim.x + threadIdx.x;
    if (i < n) { counts[i] = 0; cursor[i] = 0; }
    if (blockIdx.x == 0 && threadIdx.x < 64) {
        unsigned int v = ei[2 * threadIdx.x + 1];
        unsigned long long b = __ballot(v != 0u);
        if (threadIdx.x == 0) *flag = (b == 0ull) ? 1 : 0;
    }
}

__global__ __launch_bounds__(256) void count_kernel(const int* __restrict__ ei,
                                                    const int* __restrict__ flag,
                                                    int E, int N, int* __restrict__ counts) {
    int e = blockIdx.x * blockDim.x + threadIdx.x;
    if (e >= E + N) return;
    int is64 = *flag;
    int d = (e < E) ? edge_val(ei, is64, (long long)E + e) : (e - E);
    atomicAdd(&counts[d], 1);
}

__global__ __launch_bounds__(256) void scan_block_kernel(const int* __restrict__ counts,
                                                         int* __restrict__ ptrArr,
                                                         int* __restrict__ bsums, int N) {
    __shared__ int sh[256];
    int t = threadIdx.x, i = blockIdx.x * 256 + t;
    int v = (i < N) ? counts[i] : 0;
    sh[t] = v;
    __syncthreads();
    for (int off = 1; off < 256; off <<= 1) {
        int u = (t >= off) ? sh[t - off] : 0;
        __syncthreads();
        sh[t] += u;
        __syncthreads();
    }
    if (i < N) ptrArr[i] = sh[t] - v;
    if (t == 255) bsums[blockIdx.x] = sh[255];
}

__global__ __launch_bounds__(1024) void scan_tops_kernel(const int* __restrict__ bsums,
                                                         int* __restrict__ boff, int nb,
                                                         int* __restrict__ totalOut) {
    __shared__ int sh[1024];
    int t = threadIdx.x;
    int v = (t < nb) ? bsums[t] : 0;
    sh[t] = v;
    __syncthreads();
    for (int off = 1; off < 1024; off <<= 1) {
        int u = (t >= off) ? sh[t - off] : 0;
        __syncthreads();
        sh[t] += u;
        __syncthreads();
    }
    if (t < nb) boff[t] = sh[t] - v;
    if (t == 1023) *totalOut = sh[1023];
}

__global__ __launch_bounds__(256) void scan_add_kernel(int* __restrict__ ptrArr,
                                                       const int* __restrict__ boff, int N) {
    int i = blockIdx.x * blockDim.x + threadIdx.x;
    if (i < N) ptrArr[i] += boff[i >> 8];
}

__global__ __launch_bounds__(256) void fill_kernel(const int* __restrict__ ei,
                                                   const int* __restrict__ flag,
                                                   int E, int N,
                                                   const int* __restrict__ ptrArr,
                                                   int* __restrict__ cursor,
                                                   int* __restrict__ csr_src) {
    int e = blockIdx.x * blockDim.x + threadIdx.x;
    if (e >= E + N) return;
    int is64 = *flag;
    int s, d;
    if (e < E) {
        s = edge_val(ei, is64, e);
        d = edge_val(ei, is64, (long long)E + e);
    } else {
        s = d = e - E;
    }
    int slot = atomicAdd(&cursor[d], 1);
    csr_src[ptrArr[d] + slot] = s;
}

// ---- merged: Wt1 (bf16 transpose), Wt2, and projected attention vecs ----
__global__ __launch_bounds__(256) void prep_weights_kernel(const float* __restrict__ W1,
                                                           const float* __restrict__ W2,
                                                           const float* __restrict__ a_s,
                                                           const float* __restrict__ a_d,
                                                           unsigned short* __restrict__ Wt1,
                                                           unsigned short* __restrict__ Wt2,
                                                           float* __restrict__ ws1,
                                                           float* __restrict__ wd1) {
    int i = blockIdx.x * blockDim.x + threadIdx.x;
    if (i < 512 * 128) {
        int n = i / 128, k = i - n * 128;          // Wt1 [512][128] <- W1 [128][512]
        Wt1[i] = f2bf(W1[(size_t)k * 512 + n]);
    } else if (i < 512 * 128 + 256 * 512) {
        int j = i - 512 * 128;
        int n = j / 512, k = j - n * 512;          // Wt2 [256][512] <- W2 [512][256]
        Wt2[j] = f2bf(W2[(size_t)k * 256 + n]);
    } else if (i < 512 * 128 + 256 * 512 + 1024) {
        int t = i - 512 * 128 - 256 * 512;
        int k = t >> 3, sd = (t >> 2) & 1, h = t & 3;
        const float* a = sd ? a_d : a_s;
        float s = 0.f;
        const float* wr = W1 + (size_t)k * 512 + h * 128;
        const float* ar = a + h * 128;
        for (int c = 0; c < 128; ++c) s += wr[c] * ar[c];
        (sd ? wd1 : ws1)[k * 4 + h] = s;
    }
}

// ---- L1 alpha logits (fp32 exact) + x -> bf16 conversion fused ----
__global__ __launch_bounds__(256) void alpha_x_kernel(const float* __restrict__ x,
                                                      const float* __restrict__ ws1,
                                                      const float* __restrict__ wd1,
                                                      float* __restrict__ out_s,
                                                      float* __restrict__ out_d,
                                                      unsigned short* __restrict__ xbf, int N) {
    int lane = threadIdx.x & 63;
    int wid = threadIdx.x >> 6;
    int n = blockIdx.x * (blockDim.x >> 6) + wid;
    if (n >= N) return;
    int k0 = lane * 2;
    float2 xv = *(const float2*)(x + (size_t)n * 128 + k0);
    alignas(4) unsigned short o[2] = {f2bf(xv.x), f2bf(xv.y)};
    *(unsigned int*)(xbf + (size_t)n * 128 + k0) = *(unsigned int*)o;
    fx4 s0 = *(const fx4*)(ws1 + k0 * 4);
    fx4 s1 = *(const fx4*)(ws1 + k0 * 4 + 4);
    fx4 d0 = *(const fx4*)(wd1 + k0 * 4);
    fx4 d1 = *(const fx4*)(wd1 + k0 * 4 + 4);
    float ps[4], pd[4];
#pragma unroll
    for (int h = 0; h < 4; ++h) {
        ps[h] = xv.x * s0[h] + xv.y * s1[h];
        pd[h] = xv.x * d0[h] + xv.y * d1[h];
    }
#pragma unroll
    for (int off = 32; off; off >>= 1)
#pragma unroll
        for (int h = 0; h < 4; ++h) {
            ps[h] += __shfl_xor(ps[h], off);
            pd[h] += __shfl_xor(pd[h], off);
        }
    if (lane == 0) {
        fx4 rs = {ps[0], ps[1], ps[2], ps[3]};
        fx4 rd = {pd[0], pd[1], pd[2], pd[3]};
        *(fx4*)(out_s + (size_t)n * 4) = rs;
        *(fx4*)(out_d + (size_t)n * 4) = rd;
    }
}

// ---------------------------------------------------------------------------
// Fused softmax + aggX (layer 1): aggX[h][n][k] = sum_e alpha[e][h]*xbf[src][k].
// ---------------------------------------------------------------------------
__global__ __launch_bounds__(256) void sm_aggx_kernel(const int* __restrict__ ptrArr,
                                                      const int* __restrict__ csr_src,
                                                      const float* __restrict__ as,
                                                      const float* __restrict__ ad,
                                                      const unsigned short* __restrict__ xbf,
                                                      unsigned short* __restrict__ aggX, int N) {
    __shared__ float sal[4][64][4];
    int lane = threadIdx.x & 63;
    int wid = threadIdx.x >> 6;
    int n = blockIdx.x * 4 + wid;
    if (n >= N) return;
    int beg = ptrArr[n], end = ptrArr[n + 1];
    int deg = end - beg;
    fx4 dv = *(const fx4*)(ad + (size_t)n * 4);
    float acc[4][2];
#pragma unroll
    for (int h = 0; h < 4; ++h) { acc[h][0] = 0.f; acc[h][1] = 0.f; }

    if (deg <= 64) {
        bool act = lane < deg;
        int i = beg + (act ? lane : 0);
        int s = csr_src[i];
        fx4 av = *(const fx4*)(as + (size_t)s * 4);
        float e[4];
#pragma unroll
        for (int h = 0; h < 4; ++h) {
            float xx = av[h] + dv[h];
            xx = (xx >= 0.f) ? xx : LEAKY_SLOPE * xx;
            e[h] = act ? xx : -INFINITY;
        }
#pragma unroll
        for (int h = 0; h < 4; ++h) {
            float mm = e[h];
#pragma unroll
            for (int off = 32; off; off >>= 1) mm = fmaxf(mm, __shfl_xor(mm, off));
            float ex = __expf(e[h] - mm);
            float ss = ex;
#pragma unroll
            for (int off = 32; off; off >>= 1) ss += __shfl_xor(ss, off);
            sal[wid][lane][h] = ex / (ss + 1e-16f);
        }
        for (int i2 = beg; i2 < end; i2 += 4) {
            int r = end - i2;
            int e1 = (r > 1) ? i2 + 1 : i2;
            int e2 = (r > 2) ? i2 + 2 : i2;
            int e3 = (r > 3) ? i2 + 3 : i2;
            int s0 = csr_src[i2], s1 = csr_src[e1], s2 = csr_src[e2], s3 = csr_src[e3];
            fx4 a0 = *(const fx4*)&sal[wid][i2 - beg][0];
            fx4 a1 = *(const fx4*)&sal[wid][e1 - beg][0];
            fx4 a2 = *(const fx4*)&sal[wid][e2 - beg][0];
            fx4 a3 = *(const fx4*)&sal[wid][e3 - beg][0];
            if (r <= 1) a1 = (fx4){0.f, 0.f, 0.f, 0.f};
            if (r <= 2) a2 = (fx4){0.f, 0.f, 0.f, 0.f};
            if (r <= 3) a3 = (fx4){0.f, 0.f, 0.f, 0.f};
            unsigned int r0 = *(const unsigned int*)(xbf + (size_t)s0 * 128 + lane * 2);
            unsigned int r1 = *(const unsigned int*)(xbf + (size_t)s1 * 128 + lane * 2);
            unsigned int r2 = *(const unsigned int*)(xbf + (size_t)s2 * 128 + lane * 2);
            unsigned int r3 = *(const unsigned int*)(xbf + (size_t)s3 * 128 + lane * 2);
            float x00 = bf2f((unsigned short)r0), x01 = bf2f((unsigned short)(r0 >> 16));
            float x10 = bf2f((unsigned short)r1), x11 = bf2f((unsigned short)(r1 >> 16));
            float x20 = bf2f((unsigned short)r2), x21 = bf2f((unsigned short)(r2 >> 16));
            float x30 = bf2f((unsigned short)r3), x31 = bf2f((unsigned short)(r3 >> 16));
#pragma unroll
            for (int h = 0; h < 4; ++h) {
                acc[h][0] += a0[h] * x00 + a1[h] * x10 + a2[h] * x20 + a3[h] * x30;
                acc[h][1] += a0[h] * x01 + a1[h] * x11 + a2[h] * x21 + a3[h] * x31;
            }
        }
    } else {
        float m[4], inv[4];
#pragma unroll
        for (int h = 0; h < 4; ++h) m[h] = -INFINITY;
        for (int i = beg + lane; i < end; i += 64) {
            int s = csr_src[i];
            fx4 av = *(const fx4*)(as + (size_t)s * 4);
#pragma unroll
            for (int h = 0; h < 4; ++h) {
                float v = av[h] + dv[h];
                v = (v >= 0.f) ? v : LEAKY_SLOPE * v;
                m[h] = fmaxf(m[h], v);
            }
        }
#pragma unroll
        for (int h = 0; h < 4; ++h)
#pragma unroll
            for (int off = 32; off; off >>= 1) m[h] = fmaxf(m[h], __shfl_xor(m[h], off));
        float ss[4] = {0.f, 0.f, 0.f, 0.f};
        for (int i = beg + lane; i < end; i += 64) {
            int s = csr_src[i];
            fx4 av = *(const fx4*)(as + (size_t)s * 4);
#pragma unroll
            for (int h = 0; h < 4; ++h) {
                float v = av[h] + dv[h];
                v = (v >= 0.f) ? v : LEAKY_SLOPE * v;
                ss[h] += __expf(v - m[h]);
            }
        }
#pragma unroll
        for (int h = 0; h < 4; ++h) {
#pragma unroll
            for (int off = 32; off; off >>= 1) ss[h] += __shfl_xor(ss[h], off);
            inv[h] = 1.f / (ss[h] + 1e-16f);
        }
        for (int i = beg; i < end; ++i) {
            int s = csr_src[i];
            fx4 av = *(const fx4*)(as + (size_t)s * 4);
            unsigned int rr = *(const unsigned int*)(xbf + (size_t)s * 128 + lane * 2);
            float x0 = bf2f((unsigned short)rr), x1 = bf2f((unsigned short)(rr >> 16));
#pragma unroll
            for (int h = 0; h < 4; ++h) {
                float v = av[h] + dv[h];
                v = (v >= 0.f) ? v : LEAKY_SLOPE * v;
                float al = __expf(v - m[h]) * inv[h];
                acc[h][0] += al * x0;
                acc[h][1] += al * x1;
            }
        }
    }
#pragma unroll
    for (int h = 0; h < 4; ++h) {
        alignas(4) unsigned short o[2] = {f2bf(acc[h][0]), f2bf(acc[h][1])};
        *(unsigned int*)(aggX + (size_t)h * N * 128 + (size_t)n * 128 + lane * 2) = *(unsigned int*)o;
    }
}

// ---------------------------------------------------------------------------
// Fused GEMM1+GEMM2 — r10 config (best measured): 8 waves, 68 KB LDS,
// launch_bounds(512,4), compiler-scheduled loads. Wave w: head h=w>>1,
// half=w&1. Phase A: h1 cols [h*128+half*64,+64) = ELU(aggX_h @ W1 + b1)
// -> h1 LDS; A-fragments direct from global. Phase B: h2 cols
// [h*64+half*32,+32) = h1 @ W2 + alpha2 partials (cross-wave via scratch).
// ---------------------------------------------------------------------------
__global__ __launch_bounds__(512, 4) void fused12_kernel(const unsigned short* __restrict__ aggX,
                                                         const unsigned short* __restrict__ Wt1,
                                                         const unsigned short* __restrict__ Wt2,
                                                         const float* __restrict__ b1,
                                                         const float* __restrict__ a_src2,
                                                         const float* __restrict__ a_dst2,
                                                         unsigned short* __restrict__ h2,
                                                         float* __restrict__ a2s,
                                                         float* __restrict__ a2d,
                                                         int M) {
    __shared__ unsigned short h1[64 * 512];  // 64 KB, row stride 1024 B
    __shared__ float red[8 * 2 * 64];        // 4 KB alpha2 scratch
    const int bm = blockIdx.x;
    const int tid = threadIdx.x;
    const int lane = tid & 63, wid = tid >> 6;     // wid in [0,8)
    const int h = wid >> 1, half = wid & 1;
    const int l15 = lane & 15, l4 = lane >> 4;

    const unsigned short* plane = aggX + (size_t)h * M * 128;

    // ---- phase A: h1 cols [h*128 + half*64, +64), K=128; A direct-global ----
    {
        f32x4 acc[4][4];
#pragma unroll
        for (int m = 0; m < 4; ++m)
#pragma unroll
            for (int n = 0; n < 4; ++n) acc[m][n] = (f32x4){0.f, 0.f, 0.f, 0.f};
#pragma unroll
        for (int step = 0; step < 4; ++step) {
            bf16x8 af[4], bfr[4];
#pragma unroll
            for (int m = 0; m < 4; ++m) {
                int grow = bm * 64 + m * 16 + l15;
                if (grow >= M) grow = M - 1;
                af[m] = *(const bf16x8*)(plane + (size_t)grow * 128 + step * 32 + l4 * 8);
            }
#pragma unroll
            for (int n = 0; n < 4; ++n) {
                int rB = h * 128 + half * 64 + n * 16 + l15;
                bfr[n] = *(const bf16x8*)(Wt1 + (size_t)rB * 128 + step * 32 + l4 * 8);
            }
#pragma unroll
            for (int m = 0; m < 4; ++m)
#pragma unroll
                for (int n = 0; n < 4; ++n)
                    acc[m][n] = __builtin_amdgcn_mfma_f32_16x16x32_bf16(bfr[n], af[m], acc[m][n], 0, 0, 0);
        }
        // ELU(+bias) -> h1 LDS (XOR-swizzled rows)
#pragma unroll
        for (int m = 0; m < 4; ++m) {
            int rl = m * 16 + l15;
#pragma unroll
            for (int n = 0; n < 4; ++n) {
                int col = h * 128 + half * 64 + n * 16 + l4 * 4;
                fx4 bb = *(const fx4*)(b1 + col);
                f32x4 v = acc[m][n];
                alignas(8) unsigned short o[4];
#pragma unroll
                for (int j = 0; j < 4; ++j) o[j] = f2bf(elu(v[j] + bb[j]));
                int byteoff = (col * 2) ^ ((rl & 7) << 4);
                *(uint2*)((char*)h1 + rl * 1024 + byteoff) = *(uint2*)o;
            }
        }
    }
    __syncthreads();  // h1 complete

    // ---- phase B: h2 cols [h*64 + half*32, +32), K=512 from h1 LDS ----
    f32x4 acc2[4][2];
#pragma unroll
    for (int m = 0; m < 4; ++m)
#pragma unroll
        for (int n = 0; n < 2; ++n) acc2[m][n] = (f32x4){0.f, 0.f, 0.f, 0.f};
#pragma unroll 4
    for (int step = 0; step < 16; ++step) {
        bf16x8 af[4], bfr[2];
        int kb = step * 64 + l4 * 16;
#pragma unroll
        for (int m = 0; m < 4; ++m) {
            int rl = m * 16 + l15;
            af[m] = *(const bf16x8*)((const char*)h1 + rl * 1024 + (kb ^ ((rl & 7) << 4)));
        }
#pragma unroll
        for (int n = 0; n < 2; ++n) {
            int rB = h * 64 + half * 32 + n * 16 + l15;
            bfr[n] = *(const bf16x8*)(Wt2 + (size_t)rB * 512 + step * 32 + l4 * 8);
        }
#pragma unroll
        for (int m = 0; m < 4; ++m)
#pragma unroll
            for (int n = 0; n < 2; ++n)
                acc2[m][n] = __builtin_amdgcn_mfma_f32_16x16x32_bf16(bfr[n], af[m], acc2[m][n], 0, 0, 0);
    }
    // ---- store h2 (packed 8B) ----
#pragma unroll
    for (int m = 0; m < 4; ++m) {
        int row = bm * 64 + m * 16 + l15;
        if (row < M) {
#pragma unroll
            for (int n = 0; n < 2; ++n) {
                int col = h * 64 + half * 32 + n * 16 + l4 * 4;
                f32x4 v = acc2[m][n];
                alignas(8) unsigned short o[4] = {f2bf(v[0]), f2bf(v[1]), f2bf(v[2]), f2bf(v[3])};
                *(uint2*)(h2 + (size_t)row * 256 + col) = *(uint2*)o;
            }
        }
    }
    // ---- alpha2 partials (wave covers 32 of head h's 64 cols) ----
    float ps[4], pd[4];
#pragma unroll
    for (int m = 0; m < 4; ++m) { ps[m] = 0.f; pd[m] = 0.f; }
#pragma unroll
    for (int n = 0; n < 2; ++n) {
        int col = h * 64 + half * 32 + n * 16 + l4 * 4;
        fx4 asv = *(const fx4*)(a_src2 + col);
        fx4 adv = *(const fx4*)(a_dst2 + col);
#pragma unroll
        for (int m = 0; m < 4; ++m)
#pragma unroll
            for (int j = 0; j < 4; ++j) {
                ps[m] += acc2[m][n][j] * asv[j];
                pd[m] += acc2[m][n][j] * adv[j];
            }
    }
#pragma unroll
    for (int m = 0; m < 4; ++m) {
        ps[m] += __shfl_xor(ps[m], 16); ps[m] += __shfl_xor(ps[m], 32);
        pd[m] += __shfl_xor(pd[m], 16); pd[m] += __shfl_xor(pd[m], 32);
    }
    // cross-wave combine via LDS scratch
    if (lane < 16) {
#pragma unroll
        for (int m = 0; m < 4; ++m) {
            int rl = m * 16 + l15;
            red[(wid * 2 + 0) * 64 + rl] = ps[m];
            red[(wid * 2 + 1) * 64 + rl] = pd[m];
        }
    }
    __syncthreads();
    if (half == 0 && lane < 16) {
#pragma unroll
        for (int m = 0; m < 4; ++m) {
            int rl = m * 16 + l15;
            int row = bm * 64 + rl;
            if (row < M) {
                a2s[(size_t)row * 4 + h] = red[(wid * 2 + 0) * 64 + rl] + red[((wid + 1) * 2 + 0) * 64 + rl];
                a2d[(size_t)row * 4 + h] = red[(wid * 2 + 1) * 64 + rl] + red[((wid + 1) * 2 + 1) * 64 + rl];
            }
        }
    }
}

// ---------------------------------------------------------------------------
// Fused softmax + aggregate (layer 2) + layer-3 GEMM + alpha3 epilogue.
// ---------------------------------------------------------------------------
__global__ __launch_bounds__(256) void sm_agg2_kernel(const int* __restrict__ ptrArr,
                                                      const int* __restrict__ csr_src,
                                                      const float* __restrict__ as,
                                                      const float* __restrict__ ad,
                                                      const unsigned short* __restrict__ hmat,
                                                      const float* __restrict__ bias,
                                                      const float* __restrict__ W3,
                                                      const float* __restrict__ a_s3,
                                                      const float* __restrict__ a_d3,
                                                      float* __restrict__ h3,
                                                      float* __restrict__ alpha_s3,
                                                      float* __restrict__ alpha_d3, int N) {
    __shared__ float sal[4][64][4];
    int lane = threadIdx.x & 63;
    int wid = threadIdx.x >> 6;
    int n = blockIdx.x * 4 + wid;
    if (n >= N) return;
    int beg = ptrArr[n], end = ptrArr[n + 1];
    int deg = end - beg;
    int head = lane >> 4;
    fx4 dv = *(const fx4*)(ad + (size_t)n * 4);
    float acc[4] = {0.f, 0.f, 0.f, 0.f};

    if (deg <= 64) {
        bool act = lane < deg;
        int i = beg + (act ? lane : 0);
        int s = csr_src[i];
        fx4 av = *(const fx4*)(as + (size_t)s * 4);
        float e[4];
#pragma unroll
        for (int h = 0; h < 4; ++h) {
            float xx = av[h] + dv[h];
            xx = (xx >= 0.f) ? xx : LEAKY_SLOPE * xx;
            e[h] = act ? xx : -INFINITY;
        }
#pragma unroll
        for (int h = 0; h < 4; ++h) {
            float mm = e[h];
#pragma unroll
            for (int off = 32; off; off >>= 1) mm = fmaxf(mm, __shfl_xor(mm, off));
            float ex = __expf(e[h] - mm);
            float ss = ex;
#pragma unroll
            for (int off = 32; off; off >>= 1) ss += __shfl_xor(ss, off);
            sal[wid][lane][h] = ex / (ss + 1e-16f);
        }
        for (int i2 = beg; i2 < end; i2 += 4) {
            int r = end - i2;
            int e1 = (r > 1) ? i2 + 1 : i2;
            int e2 = (r > 2) ? i2 + 2 : i2;
            int e3 = (r > 3) ? i2 + 3 : i2;
            int s0 = csr_src[i2], s1 = csr_src[e1], s2 = csr_src[e2], s3 = csr_src[e3];
            float al0 = sal[wid][i2 - beg][head];
            float al1 = (r > 1) ? sal[wid][e1 - beg][head] : 0.f;
            float al2 = (r > 2) ? sal[wid][e2 - beg][head] : 0.f;
            float al3 = (r > 3) ? sal[wid][e3 - beg][head] : 0.f;
            alignas(8) unsigned short v0[4], v1[4], v2[4], v3[4];
            *(uint2*)v0 = *(const uint2*)(hmat + (size_t)s0 * 256 + lane * 4);
            *(uint2*)v1 = *(const uint2*)(hmat + (size_t)s1 * 256 + lane * 4);
            *(uint2*)v2 = *(const uint2*)(hmat + (size_t)s2 * 256 + lane * 4);
            *(uint2*)v3 = *(const uint2*)(hmat + (size_t)s3 * 256 + lane * 4);
#pragma unroll
            for (int t = 0; t < 4; ++t)
                acc[t] += al0 * bf2f(v0[t]) + al1 * bf2f(v1[t]) + al2 * bf2f(v2[t]) + al3 * bf2f(v3[t]);
        }
    } else {
        float m[4], inv[4];
#pragma unroll
        for (int h = 0; h < 4; ++h) m[h] = -INFINITY;
        for (int i = beg + lane; i < end; i += 64) {
            int s = csr_src[i];
            fx4 av = *(const fx4*)(as + (size_t)s * 4);
#pragma unroll
            for (int h = 0; h < 4; ++h) {
                float v = av[h] + dv[h];
                v = (v >= 0.f) ? v : LEAKY_SLOPE * v;
                m[h] = fmaxf(m[h], v);
            }
        }
#pragma unroll
        for (int h = 0; h < 4; ++h)
#pragma unroll
            for (int off = 32; off; off >>= 1) m[h] = fmaxf(m[h], __shfl_xor(m[h], off));
        float ss[4] = {0.f, 0.f, 0.f, 0.f};
        for (int i = beg + lane; i < end; i += 64) {
            int s = csr_src[i];
            fx4 av = *(const fx4*)(as + (size_t)s * 4);
#pragma unroll
            for (int h = 0; h < 4; ++h) {
                float v = av[h] + dv[h];
                v = (v >= 0.f) ? v : LEAKY_SLOPE * v;
                ss[h] += __expf(v - m[h]);
            }
        }
#pragma unroll
        for (int h = 0; h < 4; ++h) {
#pragma unroll
            for (int off = 32; off; off >>= 1) ss[h] += __shfl_xor(ss[h], off);
            inv[h] = 1.f / (ss[h] + 1e-16f);
        }
        float mh = m[head], invh = inv[head];
        float adh = dv[head];
        for (int i = beg; i < end; ++i) {
            int s = csr_src[i];
            float v = as[(size_t)s * 4 + head] + adh;
            v = (v >= 0.f) ? v : LEAKY_SLOPE * v;
            float al = __expf(v - mh) * invh;
            alignas(8) unsigned short vv[4];
            *(uint2*)vv = *(const uint2*)(hmat + (size_t)s * 256 + lane * 4);
#pragma unroll
            for (int t = 0; t < 4; ++t) acc[t] += al * bf2f(vv[t]);
        }
    }
    // ---- x3 row in registers: ELU(+bias); then layer-3 dot (2 cols) ----
    float xv[4];
#pragma unroll
    for (int t = 0; t < 4; ++t) xv[t] = elu(acc[t] + bias[lane * 4 + t]);
    int j0 = lane * 4;
    fx4 wA = *(const fx4*)(W3 + j0 * 2);
    fx4 wB = *(const fx4*)(W3 + j0 * 2 + 4);
    float p0 = xv[0] * wA[0] + xv[1] * wA[2] + xv[2] * wB[0] + xv[3] * wB[2];
    float p1 = xv[0] * wA[1] + xv[1] * wA[3] + xv[2] * wB[1] + xv[3] * wB[3];
#pragma unroll
    for (int off = 32; off; off >>= 1) {
        p0 += __shfl_xor(p0, off);
        p1 += __shfl_xor(p1, off);
    }
    if (lane == 0) {
        h3[(size_t)n * 2 + 0] = p0;
        h3[(size_t)n * 2 + 1] = p1;
        alpha_s3[n] = p0 * a_s3[0] + p1 * a_s3[1];
        alpha_d3[n] = p0 * a_d3[0] + p1 * a_d3[1];
    }
}

// ---------------------------------------------------------------------------
// Fused softmax + aggregate (layer 3, H=1, out fp32). Wave per node.
// ---------------------------------------------------------------------------
__global__ __launch_bounds__(256) void sm_agg3_kernel(const int* __restrict__ ptrArr,
                                                      const int* __restrict__ csr_src,
                                                      const float* __restrict__ as,
                                                      const float* __restrict__ ad,
                                                      const float* __restrict__ h3,
                                                      const float* __restrict__ b3,
                                                      float* __restrict__ out, int N) {
    int lane = threadIdx.x & 63;
    int wid = threadIdx.x >> 6;
    int n = blockIdx.x * 4 + wid;
    if (n >= N) return;
    int beg = ptrArr[n], end = ptrArr[n + 1];
    int deg = end - beg;
    float adv = ad[n];
    float p0 = 0.f, p1 = 0.f;
    if (deg <= 64) {
        bool act = lane < deg;
        int i = beg + (act ? lane : 0);
        int s = csr_src[i];
        float xx = as[s] + adv;
        xx = (xx >= 0.f) ? xx : LEAKY_SLOPE * xx;
        float e = act ? xx : -INFINITY;
        float mm = e;
#pragma unroll
        for (int off = 32; off; off >>= 1) mm = fmaxf(mm, __shfl_xor(mm, off));
        float ex = __expf(e - mm);
        float ss = ex;
#pragma unroll
        for (int off = 32; off; off >>= 1) ss += __shfl_xor(ss, off);
        float al = ex / (ss + 1e-16f);
        float2 hv = act ? *(const float2*)(h3 + (size_t)s * 2) : make_float2(0.f, 0.f);
        p0 = al * hv.x;
        p1 = al * hv.y;
#pragma unroll
        for (int off = 32; off; off >>= 1) {
            p0 += __shfl_xor(p0, off);
            p1 += __shfl_xor(p1, off);
        }
    } else {
        float m = -INFINITY;
        for (int i = beg + lane; i < end; i += 64) {
            int s = csr_src[i];
            float v = as[s] + adv;
            v = (v >= 0.f) ? v : LEAKY_SLOPE * v;
            m = fmaxf(m, v);
        }
#pragma unroll
        for (int off = 32; off; off >>= 1) m = fmaxf(m, __shfl_xor(m, off));
        float ss = 0.f;
        for (int i = beg + lane; i < end; i += 64) {
            int s = csr_src[i];
            float v = as[s] + adv;
            v = (v >= 0.f) ? v : LEAKY_SLOPE * v;
            ss += __expf(v - m);
        }
#pragma unroll
        for (int off = 32; off; off >>= 1) ss += __shfl_xor(ss, off);
        float inv = 1.f / (ss + 1e-16f);
        for (int i = beg + lane; i < end; i += 64) {
            int s = csr_src[i];
            float v = as[s] + adv;
            v = (v >= 0.f) ? v : LEAKY_SLOPE * v;
            float al = __expf(v - m) * inv;
            float2 hv = *(const float2*)(h3 + (size_t)s * 2);
            p0 += al * hv.x;
            p1 += al * hv.y;
        }
#pragma unroll
        for (int off = 32; off; off >>= 1) {
            p0 += __shfl_xor(p0, off);
            p1 += __shfl_xor(p1, off);
        }
    }
    if (lane == 0) {
        out[(size_t)n * 2 + 0] = p0 + b3[0];
        out[(size_t)n * 2 + 1] = p1 + b3[1];
    }
}

// ---------------------------------------------------------------------------

extern "C" void kernel_launch(void* const* d_in, const int* in_sizes, int n_in,
                              void* d_out, int out_size, void* d_ws, size_t ws_size,
                              hipStream_t stream) {
    const float* x      = (const float*)d_in[0];
    const int*   ei     = (const int*)d_in[1];
    const float* W1     = (const float*)d_in[2];
    const float* a_src1 = (const float*)d_in[3];
    const float* a_dst1 = (const float*)d_in[4];
    const float* b1     = (const float*)d_in[5];
    const float* W2     = (const float*)d_in[6];
    const float* a_src2 = (const float*)d_in[7];
    const float* a_dst2 = (const float*)d_in[8];
    const float* b2     = (const float*)d_in[9];
    const float* W3     = (const float*)d_in[10];
    const float* a_src3 = (const float*)d_in[11];
    const float* a_dst3 = (const float*)d_in[12];
    const float* b3     = (const float*)d_in[13];

    const int N = in_sizes[0] / 128;
    const int E = in_sizes[1] / 2;
    const int ET = E + N;
    const int nb = (N + 255) / 256;

    size_t need = 0;
    auto carve = [&](size_t bytes) -> size_t {
        size_t off = need;
        need += (bytes + 255) & ~(size_t)255;
        return off;
    };
    size_t o_counts   = carve((size_t)N * 4);
    size_t o_cursor   = carve((size_t)N * 4);
    size_t o_ptr      = carve((size_t)(N + 1) * 4);
    size_t o_csr      = carve((size_t)ET * 4);
    size_t o_flag     = carve(4);
    size_t o_bsums    = carve((size_t)2048 * 4);
    size_t o_boff     = carve((size_t)2048 * 4);
    size_t o_alpha_s  = carve((size_t)N * 4 * 4);
    size_t o_alpha_d  = carve((size_t)N * 4 * 4);
    size_t o_a2s      = carve((size_t)N * 4 * 4);
    size_t o_a2d      = carve((size_t)N * 4 * 4);
    size_t o_a3s      = carve((size_t)N * 4);
    size_t o_a3d      = carve((size_t)N * 4);
    size_t o_h3       = carve((size_t)N * 2 * 4);
    size_t o_wsd      = carve((size_t)128 * 4 * 4 * 2);  // ws1 + wd1
    size_t o_wt1      = carve((size_t)512 * 128 * 2);
    size_t o_wt2      = carve((size_t)256 * 512 * 2);
    size_t o_xbf      = carve((size_t)N * 128 * 2);
    size_t o_bufA     = carve((size_t)N * 512 * 2);
    size_t o_bufB     = carve((size_t)N * 512 * 2);

    if (need > ws_size) {
        sentinel_kernel<<<(out_size + 255) / 256, 256, 0, stream>>>(
            (float*)d_out, out_size, (float)(ws_size >> 20));
        return;
    }

    char* w = (char*)d_ws;
    int*   counts   = (int*)(w + o_counts);
    int*   cursor   = (int*)(w + o_cursor);
    int*   ptrArr   = (int*)(w + o_ptr);
    int*   csr_src  = (int*)(w + o_csr);
    int*   flag     = (int*)(w + o_flag);
    int*   bsums    = (int*)(w + o_bsums);
    int*   boff     = (int*)(w + o_boff);
    float* alpha_s  = (float*)(w + o_alpha_s);
    float* alpha_d  = (float*)(w + o_alpha_d);
    float* a2s      = (float*)(w + o_a2s);
    float* a2d      = (float*)(w + o_a2d);
    float* a3s      = (float*)(w + o_a3s);
    float* a3d      = (float*)(w + o_a3d);
    float* h3       = (float*)(w + o_h3);
    float* ws1      = (float*)(w + o_wsd);
    float* wd1      = ws1 + 128 * 4;
    unsigned short* Wt1  = (unsigned short*)(w + o_wt1);
    unsigned short* Wt2  = (unsigned short*)(w + o_wt2);
    unsigned short* xbf  = (unsigned short*)(w + o_xbf);
    unsigned short* bufA = (unsigned short*)(w + o_bufA);
    unsigned short* bufB = (unsigned short*)(w + o_bufB);

    const int edge_blocks = (ET + 255) / 256;
    const int node_wave_blocks = (N + 3) / 4;
    const int node_thr_blocks = (N + 255) / 256;

    // ---- CSR build ----
    prep_graph_kernel<<<node_thr_blocks, 256, 0, stream>>>((const unsigned int*)ei, flag, counts, cursor, N);
    count_kernel<<<edge_blocks, 256, 0, stream>>>(ei, flag, E, N, counts);
    scan_block_kernel<<<nb, 256, 0, stream>>>(counts, ptrArr, bsums, N);
    scan_tops_kernel<<<1, 1024, 0, stream>>>(bsums, boff, nb, ptrArr + N);
    scan_add_kernel<<<node_thr_blocks, 256, 0, stream>>>(ptrArr, boff, N);
    fill_kernel<<<edge_blocks, 256, 0, stream>>>(ei, flag, E, N, ptrArr, cursor, csr_src);

    // ---- precomputes (merged) ----
    prep_weights_kernel<<<(512 * 128 + 256 * 512 + 1024 + 255) / 256, 256, 0, stream>>>(
        W1, W2, a_src1, a_dst1, Wt1, Wt2, ws1, wd1);

    // ---- alpha1 logits + x->bf16 ----
    alpha_x_kernel<<<node_wave_blocks, 256, 0, stream>>>(x, ws1, wd1, alpha_s, alpha_d, xbf, N);

    // ---- L1 softmax+gather -> aggX (head-major, bufA) ----
    sm_aggx_kernel<<<node_wave_blocks, 256, 0, stream>>>(ptrArr, csr_src, alpha_s, alpha_d, xbf, bufA, N);

    // ---- Fused GEMM1+GEMM2: aggX(bufA) -> h2(bufB) + alpha2 ----
    fused12_kernel<<<(N + 63) / 64, 512, 0, stream>>>(bufA, Wt1, Wt2, b1,
                                                      a_src2, a_dst2, bufB,
                                                      a2s, a2d, N);

    // ---- Layer 2 back half + layer-3 GEMM + alpha3 ----
    sm_agg2_kernel<<<node_wave_blocks, 256, 0, stream>>>(ptrArr, csr_src, a2s, a2d,
                                                         bufB, b2, W3, a_src3, a_dst3,
                                                         h3, a3s, a3d, N);

    // ---- Layer 3 aggregate ----
    sm_agg3_kernel<<<node_wave_blocks, 256, 0, stream>>>(ptrArr, csr_src, a3s, a3d, h3, b3, (float*)d_out, N);
}